// Round 2
// baseline (118.706 us; speedup 1.0000x reference)
//
#include <hip/hip_runtime.h>
#include <stdint.h>

#define NPIX  (512 * 512)
#define NB    8
#define NCH   32                 // fine-hist chunks per batch
#define CHPX  (NPIX / NCH)       // 8192 px per chunk (u16 cell counts can't overflow)
#define FB    128                // fine bins per axis (2 per coarse bin)
#define MPW   161                // padded mid row width: 16 guard + 128 + 17 guard
#define HDR_FLOATS 1024          // ws: [0,512) minmax, [512,520) mi, [520,532) counters

typedef __attribute__((ext_vector_type(4))) unsigned uint4v;
typedef __attribute__((ext_vector_type(4))) float    float4v;

// 33-tap Gaussian conv kernel, w[k] = exp(-(16-k)^2/8)  (sigma=1 bin, fine=1/2 bin)
__device__ constexpr float WK[33] = {
  1.2664166e-14f, 6.1019365e-13f, 2.2897490e-11f, 6.6915858e-10f,
  1.5229979e-08f, 2.6995785e-07f, 3.7266532e-06f, 4.0065297e-05f,
  3.3546263e-04f, 2.1874911e-03f, 1.1108997e-02f, 4.3936934e-02f,
  1.3533528e-01f, 3.2465247e-01f, 6.0653066e-01f, 8.8249690e-01f,
  1.0f,
  8.8249690e-01f, 6.0653066e-01f, 3.2465247e-01f, 1.3533528e-01f,
  4.3936934e-02f, 1.1108997e-02f, 2.1874911e-03f, 3.3546263e-04f,
  4.0065297e-05f, 3.7266532e-06f, 2.6995785e-07f, 1.5229979e-08f,
  6.6915858e-10f, 2.2897490e-11f, 6.1019365e-13f, 1.2664166e-14f
};

// ---- kernel 1: per-block min/max partials; re-arms all tail counters ----
__global__ __launch_bounds__(1024) void minmax_kernel(const float* __restrict__ pred,
                                                      const float* __restrict__ tgt,
                                                      float2* __restrict__ mm,
                                                      unsigned* __restrict__ cnt) {
  __shared__ float smin[16], smax[16];
  const int tid = threadIdx.x, lane = tid & 63, wave = tid >> 6;
  if (blockIdx.x == 0 && tid < 12) cnt[tid] = 0u;   // re-armed every launch/replay
  const int pair = blockIdx.x >> 4, sub = blockIdx.x & 15;
  const float* src = pair < 8 ? pred + (size_t)pair * NPIX
                              : tgt  + (size_t)(pair - 8) * NPIX;
  const float4v* s4 = (const float4v*)src + sub * 4096;
  float vmin = 3.0e38f, vmax = -3.0e38f;
  #pragma unroll
  for (int k = 0; k < 4; ++k) {
    float4v v = s4[k * 1024 + tid];
    vmin = fminf(vmin, fminf(fminf(v[0], v[1]), fminf(v[2], v[3])));
    vmax = fmaxf(vmax, fmaxf(fmaxf(v[0], v[1]), fmaxf(v[2], v[3])));
  }
  #pragma unroll
  for (int off = 32; off; off >>= 1) {
    vmin = fminf(vmin, __shfl_xor(vmin, off));
    vmax = fmaxf(vmax, __shfl_xor(vmax, off));
  }
  if (lane == 0) { smin[wave] = vmin; smax[wave] = vmax; }
  __syncthreads();
  if (tid == 0) {
    float m = smin[0], M = smax[0];
    #pragma unroll
    for (int w = 1; w < 16; ++w) { m = fminf(m, smin[w]); M = fmaxf(M, smax[w]); }
    mm[blockIdx.x] = (float2){m, M};
  }
}

// ---- kernel 2 (mega): fine hist -> part -> per-batch counter barrier ->
//      32-chunk reduce (overlapped across batches) -> counter barrier ->
//      blocks 0-7: conv1+conv2+marginals+MI+final mean. 256 blocks x 1024 thr.
// Barriers are NON-BLOCKING for completion: every block arrives at its counter
// unconditionally; only blocks that need the data spin. Per-batch spinners wait
// on their own 32 co-dispatched siblings (256 blocks <= 256 CUs, all resident);
// the final spin involves only blocks 0-7. Deadlock-free by construction.
// Counters re-armed each launch by minmax_kernel (stream-ordered).
__global__ __launch_bounds__(1024) void mega_kernel(const float* __restrict__ pred,
                                                    const float* __restrict__ tgt,
                                                    const float2* __restrict__ mm,
                                                    unsigned* __restrict__ part,
                                                    float2* __restrict__ fineF,
                                                    unsigned* __restrict__ cnt,
                                                    float* __restrict__ mi,
                                                    float* __restrict__ out) {
  __shared__ float S[14608];   // tail layout; phases 1-2 alias it as u32 H[]
  unsigned* H = (unsigned*)S;
  const int tid = threadIdx.x, lane = tid & 63, wave = tid >> 6;
  const int blk = blockIdx.x;
  const int b = blk >> 5, c = blk & 31;

  // per-batch affine bin map from minmax partials
  float pmin = 3.0e38f, pmax = -3.0e38f, tmin = 3.0e38f, tmax = -3.0e38f;
  #pragma unroll
  for (int s2 = 0; s2 < 16; ++s2) {
    float2 a = mm[b * 16 + s2], d = mm[(8 + b) * 16 + s2];
    pmin = fminf(pmin, a.x); pmax = fmaxf(pmax, a.y);
    tmin = fminf(tmin, d.x); tmax = fmaxf(tmax, d.y);
  }
  const float sp = 126.0f / (pmax - pmin + 1e-10f), op = -pmin * sp + 0.5f;
  const float st = 126.0f / (tmax - tmin + 1e-10f), ot = -tmin * st + 0.5f;

  // ---- phase 1: 128x128 fine hist of chunk (b,c) in LDS (u16 pairs) ----
  ((uint4v*)H)[tid]        = (uint4v){0u, 0u, 0u, 0u};
  ((uint4v*)H)[1024 + tid] = (uint4v){0u, 0u, 0u, 0u};
  __syncthreads();

  const float4v* p4 = (const float4v*)(pred + (size_t)b * NPIX + (size_t)c * CHPX);
  const float4v* t4 = (const float4v*)(tgt  + (size_t)b * NPIX + (size_t)c * CHPX);
  #pragma unroll
  for (int it = 0; it < 2; ++it) {
    float4v vp = p4[it * 1024 + tid];
    float4v vt = t4[it * 1024 + tid];
    #pragma unroll
    for (int j = 0; j < 4; ++j) {
      int fp = (int)(vp[j] * sp + op);      // 0..126
      int ft = (int)(vt[j] * st + ot);
      int w  = (fp << 6) | (ft >> 1);
      atomicAdd(&H[w ^ ((fp & 7) << 2)], 1u << ((ft & 1) << 4));  // bank-swizzled
    }
  }
  __syncthreads();

  // flush (un-swizzled, so part layout is linear)
  {
    uint4v* dst = (uint4v*)(part + ((size_t)blk << 13));
    #pragma unroll
    for (int j = 0; j < 2; ++j) {
      int g = j * 1024 + tid;
      dst[g] = ((uint4v*)H)[g ^ ((g >> 4) & 7)];
    }
  }
  __syncthreads();                        // all flush stores issued
  if (tid == 0) {
    __threadfence();                      // release part[] device-wide
    atomicAdd(&cnt[b], 1u);
    while (atomicAdd(&cnt[b], 0u) < 32u) __builtin_amdgcn_s_sleep(1);
  }
  __syncthreads();
  __threadfence();                        // acquire: siblings' part[] writes

  // ---- phase 2: reduce 32 chunk partials for slice c of batch b ----
  {
    const int w = tid & 255, q = tid >> 8;     // 4 thread-groups x 8 chunks
    const unsigned* src = part + ((size_t)b << 18) + (size_t)(c * 256 + w);
    unsigned lo = 0, hi = 0;
    #pragma unroll
    for (int k = 0; k < 8; ++k) {
      unsigned v = src[(size_t)((q << 3) + k) << 13];
      lo += v & 0xFFFFu; hi += v >> 16;
    }
    H[q * 256 + w] = lo;
    H[1024 + q * 256 + w] = hi;
  }
  __syncthreads();
  if (tid < 256) {                             // exact integer regroup (bit-identical)
    unsigned lo = 0, hi = 0;
    #pragma unroll
    for (int q = 0; q < 4; ++q) { lo += H[q * 256 + tid]; hi += H[1024 + q * 256 + tid]; }
    float2 o; o.x = (float)lo; o.y = (float)hi;   // counts < 2^24: exact
    fineF[(size_t)b * 8192 + c * 256 + tid] = o;
  }
  __syncthreads();                        // fineF stores issued
  if (tid == 0) {
    __threadfence();                      // release fineF device-wide
    atomicAdd(&cnt[8], 1u);
  }
  if (blk >= 8) return;                   // only blocks 0-7 run the tail

  const int tb = blk;                     // tail batch
  if (tid == 0) {
    while (atomicAdd(&cnt[8], 0u) < 256u) __builtin_amdgcn_s_sleep(1);
  }
  __syncthreads();
  __threadfence();                        // acquire: all fineF writes

  // ---- phase 3a: conv along fine-p rows, decimate x2 -> S[0,10304) ----
  const float* fineG = (const float*)fineF;    // f32 [b][128][128] flat
  {
    const int ft = tid & 127, r = tid >> 7;
    const float* fb = fineG + ((size_t)tb << 14) + ft;
    float v[47];
    #pragma unroll
    for (int t = 0; t < 47; ++t) {
      int fp = 16 * r - 16 + t;
      v[t] = ((unsigned)fp < 128u) ? fb[fp << 7] : 0.0f;
    }
    float acc[8];
    #pragma unroll
    for (int d = 0; d < 8; ++d) {
      float a = 0.0f;
      #pragma unroll
      for (int k = 0; k < 33; ++k) a += WK[k] * v[2 * d + k];
      acc[d] = a;
    }
    #pragma unroll
    for (int d = 0; d < 8; ++d)
      S[(8 * r + d) * MPW + ft + 16] = acc[d];
    // zero guard columns: 64 rows x (16 left + 17 right)
    #pragma unroll
    for (int ii = 0; ii < 3; ++ii) {
      int idx = ii * 1024 + tid;
      if (idx < 64 * 33) {
        int rr = idx / 33, cc = idx % 33;
        int col = cc < 16 ? cc : cc + 128;
        S[rr * MPW + col] = 0.0f;
      }
    }
  }
  __syncthreads();

  // ---- phase 3b: conv along fine-t axis -> pxy ----
  const int i = tid & 63, js = (tid >> 6) << 2;
  {
    float v[39];
    #pragma unroll
    for (int t = 0; t < 39; ++t) v[t] = S[i * MPW + 2 * js + t];
    float acc[4] = {0.0f, 0.0f, 0.0f, 0.0f};
    #pragma unroll
    for (int d = 0; d < 4; ++d)
      #pragma unroll
      for (int k = 0; k < 33; ++k) acc[d] += WK[k] * v[2 * d + k];
    const float invN = 1.0f / (float)NPIX;
    #pragma unroll
    for (int d = 0; d < 4; ++d) S[10304 + i * 65 + js + d] = acc[d] * invN;
  }
  __syncthreads();

  // marginals: wave w owns 4 rows + 4 cols (16-lane groups)
  {
    const int l16 = lane & 15, sub16 = lane >> 4;
    int row = 4 * wave + sub16;
    float s = 0.0f;
    #pragma unroll
    for (int k = 0; k < 4; ++k) s += S[10304 + row * 65 + l16 * 4 + k];
    #pragma unroll
    for (int off = 8; off; off >>= 1) s += __shfl_xor(s, off);
    if (l16 == 0) S[14464 + row] = s;     // px
    float t2 = 0.0f;
    #pragma unroll
    for (int k = 0; k < 4; ++k) t2 += S[10304 + (l16 * 4 + k) * 65 + row];
    #pragma unroll
    for (int off = 8; off; off >>= 1) t2 += __shfl_xor(t2, off);
    if (l16 == 0) S[14528 + row] = t2;    // py
  }
  __syncthreads();

  float a = 0.0f;
  #pragma unroll
  for (int r = 0; r < 4; ++r) {
    int e = r * 1024 + tid;
    int ii = e >> 6, jj = e & 63;
    float pv = S[10304 + ii * 65 + jj];
    float d = S[14464 + ii] * S[14528 + jj] + 1e-10f;
    a += pv * __logf((pv + 1e-10f) / d);
  }
  #pragma unroll
  for (int off = 32; off; off >>= 1) a += __shfl_xor(a, off);
  if (lane == 0) S[14592 + wave] = a;
  __syncthreads();

  if (tid == 0) {
    float s = 0.0f;
    #pragma unroll
    for (int w = 0; w < 16; ++w) s += S[14592 + w];
    atomicExch(&mi[tb], s);               // device-scope atomic store
    __threadfence();                      // release: mi visible before counter
    unsigned prev = atomicAdd(&cnt[9], 1u);
    if (prev == NB - 1) {                 // last tail block finalizes
      __threadfence();                    // acquire
      float tot = 0.0f;
      #pragma unroll
      for (int k = 0; k < NB; ++k) tot += atomicAdd(&mi[k], 0.0f);  // atomic read
      out[0] = -(tot * (1.0f / NB));
    }
  }
}

extern "C" void kernel_launch(void* const* d_in, const int* in_sizes, int n_in,
                              void* d_out, int out_size, void* d_ws, size_t ws_size,
                              hipStream_t stream) {
  const float* pred = (const float*)d_in[0];
  const float* tgt  = (const float*)d_in[1];
  float*    out  = (float*)d_out;
  float*    wsf  = (float*)d_ws;
  float2*   mm   = (float2*)d_ws;                      // 256 float2 in [0,512) floats
  float*    mi   = wsf + 512;                          // 8 floats
  unsigned* cnt  = (unsigned*)(wsf + 520);             // [0..7] batch, [8] reduce, [9] final
  unsigned* part = (unsigned*)(wsf + HDR_FLOATS);      // NB*NCH*8192 words = 8MB
  float2*   fineF = (float2*)(wsf + HDR_FLOATS + (size_t)NB * NCH * 8192);  // NB*8192 f2

  minmax_kernel<<<256, 1024, 0, stream>>>(pred, tgt, mm, cnt);
  mega_kernel  <<<256, 1024, 0, stream>>>(pred, tgt, mm, part, fineF, cnt, mi, out);
}

// Round 3
// 38.355 us; speedup vs baseline: 3.0950x; 3.0950x over previous
//
#include <hip/hip_runtime.h>
#include <stdint.h>

#define NPIX  (512 * 512)
#define NB    8
#define NCH   32                 // fine-hist chunks per batch
#define CHPX  (NPIX / NCH)       // 8192 px per chunk (u16 cell counts can't overflow)
#define FB    128                // fine bins per axis (2 per coarse bin)
#define MPW   161                // padded mid row width: 16 guard + 128 + 17 guard
#define HDR_FLOATS 1024          // ws: [0,512) minmax, [512,520) mi, [520,..) cnt

typedef __attribute__((ext_vector_type(4))) unsigned uint4v;
typedef __attribute__((ext_vector_type(4))) float    float4v;

// 33-tap Gaussian conv kernel, w[k] = exp(-(16-k)^2/8)  (sigma=1 bin, fine=1/2 bin)
__device__ constexpr float WK[33] = {
  1.2664166e-14f, 6.1019365e-13f, 2.2897490e-11f, 6.6915858e-10f,
  1.5229979e-08f, 2.6995785e-07f, 3.7266532e-06f, 4.0065297e-05f,
  3.3546263e-04f, 2.1874911e-03f, 1.1108997e-02f, 4.3936934e-02f,
  1.3533528e-01f, 3.2465247e-01f, 6.0653066e-01f, 8.8249690e-01f,
  1.0f,
  8.8249690e-01f, 6.0653066e-01f, 3.2465247e-01f, 1.3533528e-01f,
  4.3936934e-02f, 1.1108997e-02f, 2.1874911e-03f, 3.3546263e-04f,
  4.0065297e-05f, 3.7266532e-06f, 2.6995785e-07f, 1.5229979e-08f,
  6.6915858e-10f, 2.2897490e-11f, 6.1019365e-13f, 1.2664166e-14f
};

// ---- kernel 1: per-block min/max partials; zeroes fineW; re-arms cnt ----
__global__ __launch_bounds__(1024) void minmax_kernel(const float* __restrict__ pred,
                                                      const float* __restrict__ tgt,
                                                      float2* __restrict__ mm,
                                                      unsigned* __restrict__ fineW,
                                                      unsigned* __restrict__ cnt) {
  __shared__ float smin[16], smax[16];
  const int tid = threadIdx.x, lane = tid & 63, wave = tid >> 6;
  if (blockIdx.x == 0 && tid < 4) cnt[tid] = 0u;      // re-armed every launch/replay
  // zero this block's 2KB slice of the global fine histogram (512KB total)
  if (tid < 128)
    ((uint4v*)fineW)[blockIdx.x * 128 + tid] = (uint4v){0u, 0u, 0u, 0u};
  const int pair = blockIdx.x >> 4, sub = blockIdx.x & 15;
  const float* src = pair < 8 ? pred + (size_t)pair * NPIX
                              : tgt  + (size_t)(pair - 8) * NPIX;
  const float4v* s4 = (const float4v*)src + sub * 4096;
  float vmin = 3.0e38f, vmax = -3.0e38f;
  #pragma unroll
  for (int k = 0; k < 4; ++k) {
    float4v v = s4[k * 1024 + tid];
    vmin = fminf(vmin, fminf(fminf(v[0], v[1]), fminf(v[2], v[3])));
    vmax = fmaxf(vmax, fmaxf(fmaxf(v[0], v[1]), fmaxf(v[2], v[3])));
  }
  #pragma unroll
  for (int off = 32; off; off >>= 1) {
    vmin = fminf(vmin, __shfl_xor(vmin, off));
    vmax = fmaxf(vmax, __shfl_xor(vmax, off));
  }
  if (lane == 0) { smin[wave] = vmin; smax[wave] = vmax; }
  __syncthreads();
  if (tid == 0) {
    float m = smin[0], M = smax[0];
    #pragma unroll
    for (int w = 1; w < 16; ++w) { m = fminf(m, smin[w]); M = fmaxf(M, smax[w]); }
    mm[blockIdx.x] = (float2){m, M};
  }
}

// ---- kernel 2: 2D fine histogram (128x128) per (batch, chunk) ----
// NB*NCH = 256 blocks x 512 thr. LDS: 8192 u32 words, 2 u16 cells per word,
// bank-swizzled (w ^= (fp&7)<<2). Flush: direct global atomicAdd into the
// per-batch u32 histogram fineW[b][128][128], skipping zero cells (the joint
// hist is concentrated, so most cells are zero -> exec-mask kills them).
// Integer adds in any order are exact -> downstream values bit-identical.
__global__ __launch_bounds__(512) void fine_hist_kernel(const float* __restrict__ pred,
                                                        const float* __restrict__ tgt,
                                                        const float2* __restrict__ mm,
                                                        unsigned* __restrict__ fineW) {
  __shared__ unsigned H[FB * FB / 2];   // 32KB
  const int tid = threadIdx.x;
  const int b = blockIdx.x >> 5, c = blockIdx.x & 31;

  float pmin = 3.0e38f, pmax = -3.0e38f, tmin = 3.0e38f, tmax = -3.0e38f;
  #pragma unroll
  for (int s2 = 0; s2 < 16; ++s2) {
    float2 a = mm[b * 16 + s2], d = mm[(8 + b) * 16 + s2];
    pmin = fminf(pmin, a.x); pmax = fmaxf(pmax, a.y);
    tmin = fminf(tmin, d.x); tmax = fmaxf(tmax, d.y);
  }
  // fine index f = round(t*2), t = 63*(x-min)/(range+eps):  f = x*sp + op
  const float sp = 126.0f / (pmax - pmin + 1e-10f), op = -pmin * sp + 0.5f;
  const float st = 126.0f / (tmax - tmin + 1e-10f), ot = -tmin * st + 0.5f;

  #pragma unroll
  for (int j = 0; j < 4; ++j)
    ((uint4v*)H)[j * 512 + tid] = (uint4v){0u, 0u, 0u, 0u};
  __syncthreads();

  const float4v* p4 = (const float4v*)(pred + (size_t)b * NPIX + (size_t)c * CHPX);
  const float4v* t4 = (const float4v*)(tgt  + (size_t)b * NPIX + (size_t)c * CHPX);
  #pragma unroll
  for (int it = 0; it < 4; ++it) {
    float4v vp = p4[it * 512 + tid];
    float4v vt = t4[it * 512 + tid];
    #pragma unroll
    for (int j = 0; j < 4; ++j) {
      int fp = (int)(vp[j] * sp + op);      // 0..126
      int ft = (int)(vt[j] * st + ot);
      int w  = (fp << 6) | (ft >> 1);
      atomicAdd(&H[w ^ ((fp & 7) << 2)], 1u << ((ft & 1) << 4));  // bank-swizzled
    }
  }
  __syncthreads();

  // flush: un-swizzle, unpack u16 pair, global atomic add (skip zeros)
  unsigned* fw = fineW + ((size_t)b << 14);
  #pragma unroll
  for (int j = 0; j < 16; ++j) {
    int w = j * 512 + tid;                       // logical word 0..8191
    unsigned v = H[w ^ (((w >> 6) & 7) << 2)];   // same XOR const per wave: conflict-free
    if (v) {
      int cell = ((w >> 6) << 7) | ((w & 63) << 1);   // fp*128 + 2*ftpair
      unsigned lo = v & 0xFFFFu, hi = v >> 16;
      if (lo) atomicAdd(&fw[cell], lo);
      if (hi) atomicAdd(&fw[cell + 1], hi);
    }
  }
}

// ---- kernel 3 (fused tail): conv1 (fine-p axis, decimate x2) -> mid in LDS ->
//      conv2 (fine-t axis) -> marginals -> MI -> last-block final mean ----
// NB = 8 blocks x 1024 thr. u32 counts -> f32 (counts < 2^24: exact, identical
// values to the old float pipeline). Final mean via device-scope atomics +
// counter; counter re-armed by minmax each launch (replay-safe).
__global__ __launch_bounds__(1024) void tail_kernel(const unsigned* __restrict__ fineW,
                                                    float* __restrict__ mi,
                                                    unsigned* __restrict__ cnt,
                                                    float* __restrict__ out) {
  __shared__ float S[14608];   // [0,10304) mid[64][161] | [10304,14464) pxy[64][65]
                               // | 14464 px | 14528 py | 14592 wred
  const int tid = threadIdx.x, lane = tid & 63, wave = tid >> 6;
  const int b = blockIdx.x;

  // ---- phase A: conv along fine-p rows, decimate x2 -> S[0,10304) ----
  {
    const int ft = tid & 127, r = tid >> 7;
    const unsigned* fb = fineW + ((size_t)b << 14) + ft;
    float v[47];
    #pragma unroll
    for (int t = 0; t < 47; ++t) {
      int fp = 16 * r - 16 + t;
      v[t] = ((unsigned)fp < 128u) ? (float)fb[fp << 7] : 0.0f;
    }
    float acc[8];
    #pragma unroll
    for (int d = 0; d < 8; ++d) {
      float a = 0.0f;
      #pragma unroll
      for (int k = 0; k < 33; ++k) a += WK[k] * v[2 * d + k];
      acc[d] = a;
    }
    #pragma unroll
    for (int d = 0; d < 8; ++d)
      S[(8 * r + d) * MPW + ft + 16] = acc[d];
    // zero guard columns: 64 rows x (16 left + 17 right)
    #pragma unroll
    for (int ii = 0; ii < 3; ++ii) {
      int idx = ii * 1024 + tid;
      if (idx < 64 * 33) {
        int rr = idx / 33, cc = idx % 33;
        int col = cc < 16 ? cc : cc + 128;
        S[rr * MPW + col] = 0.0f;
      }
    }
  }
  __syncthreads();

  // ---- phase B: conv along fine-t axis -> pxy ----
  const int i = tid & 63, js = (tid >> 6) << 2;
  {
    float v[39];
    #pragma unroll
    for (int t = 0; t < 39; ++t) v[t] = S[i * MPW + 2 * js + t];
    float acc[4] = {0.0f, 0.0f, 0.0f, 0.0f};
    #pragma unroll
    for (int d = 0; d < 4; ++d)
      #pragma unroll
      for (int k = 0; k < 33; ++k) acc[d] += WK[k] * v[2 * d + k];
    const float invN = 1.0f / (float)NPIX;
    #pragma unroll
    for (int d = 0; d < 4; ++d) S[10304 + i * 65 + js + d] = acc[d] * invN;
  }
  __syncthreads();

  // marginals: wave w owns 4 rows + 4 cols (16-lane groups)
  {
    const int l16 = lane & 15, sub16 = lane >> 4;
    int row = 4 * wave + sub16;
    float s = 0.0f;
    #pragma unroll
    for (int k = 0; k < 4; ++k) s += S[10304 + row * 65 + l16 * 4 + k];
    #pragma unroll
    for (int off = 8; off; off >>= 1) s += __shfl_xor(s, off);
    if (l16 == 0) S[14464 + row] = s;     // px
    float t2 = 0.0f;
    #pragma unroll
    for (int k = 0; k < 4; ++k) t2 += S[10304 + (l16 * 4 + k) * 65 + row];
    #pragma unroll
    for (int off = 8; off; off >>= 1) t2 += __shfl_xor(t2, off);
    if (l16 == 0) S[14528 + row] = t2;    // py
  }
  __syncthreads();

  float a = 0.0f;
  #pragma unroll
  for (int r = 0; r < 4; ++r) {
    int e = r * 1024 + tid;
    int ii = e >> 6, jj = e & 63;
    float pv = S[10304 + ii * 65 + jj];
    float d = S[14464 + ii] * S[14528 + jj] + 1e-10f;
    a += pv * __logf((pv + 1e-10f) / d);
  }
  #pragma unroll
  for (int off = 32; off; off >>= 1) a += __shfl_xor(a, off);
  if (lane == 0) S[14592 + wave] = a;
  __syncthreads();

  if (tid == 0) {
    float s = 0.0f;
    #pragma unroll
    for (int w = 0; w < 16; ++w) s += S[14592 + w];
    atomicExch(&mi[b], s);                 // device-scope atomic store
    __threadfence();                       // release: mi visible before counter
    unsigned prev = atomicAdd(cnt, 1u);
    if (prev == NB - 1) {                  // last block finalizes
      __threadfence();                     // acquire
      float tot = 0.0f;
      #pragma unroll
      for (int k = 0; k < NB; ++k) tot += atomicAdd(&mi[k], 0.0f);  // atomic read
      out[0] = -(tot * (1.0f / NB));
      atomicExch(cnt, 0u);                 // self-reset (replay safety)
    }
  }
}

extern "C" void kernel_launch(void* const* d_in, const int* in_sizes, int n_in,
                              void* d_out, int out_size, void* d_ws, size_t ws_size,
                              hipStream_t stream) {
  const float* pred = (const float*)d_in[0];
  const float* tgt  = (const float*)d_in[1];
  float*    out  = (float*)d_out;
  float*    wsf  = (float*)d_ws;
  float2*   mm   = (float2*)d_ws;                      // 256 float2 in [0,512) floats
  float*    mi   = wsf + 512;                          // 8 floats
  unsigned* cnt  = (unsigned*)(wsf + 520);             // tail completion counter
  unsigned* fineW = (unsigned*)(wsf + HDR_FLOATS);     // NB*16384 u32 = 512KB

  minmax_kernel   <<<256,      1024, 0, stream>>>(pred, tgt, mm, fineW, cnt);
  fine_hist_kernel<<<NB * NCH,  512, 0, stream>>>(pred, tgt, mm, fineW);
  tail_kernel     <<<NB,       1024, 0, stream>>>(fineW, mi, cnt, out);
}

// Round 4
// 33.578 us; speedup vs baseline: 3.5352x; 1.1422x over previous
//
#include <hip/hip_runtime.h>
#include <stdint.h>

#define NPIX  (512 * 512)
#define NB    8
#define NCH   8                  // fine-hist chunks per batch
#define CHPX  (NPIX / NCH)       // 32768 px per chunk (u16 cell max 32768 < 65536)
#define FB    128                // fine bins per axis (2 per coarse bin)
#define MPW   161                // padded mid row width: 16 guard + 128 + 17 guard
#define HDR_FLOATS 1024          // ws: [0,512) minmax, [512,520) mi, [520,532) cnt

typedef __attribute__((ext_vector_type(4))) unsigned uint4v;
typedef __attribute__((ext_vector_type(4))) float    float4v;

// 33-tap Gaussian conv kernel, w[k] = exp(-(16-k)^2/8)  (sigma=1 bin, fine=1/2 bin)
__device__ constexpr float WK[33] = {
  1.2664166e-14f, 6.1019365e-13f, 2.2897490e-11f, 6.6915858e-10f,
  1.5229979e-08f, 2.6995785e-07f, 3.7266532e-06f, 4.0065297e-05f,
  3.3546263e-04f, 2.1874911e-03f, 1.1108997e-02f, 4.3936934e-02f,
  1.3533528e-01f, 3.2465247e-01f, 6.0653066e-01f, 8.8249690e-01f,
  1.0f,
  8.8249690e-01f, 6.0653066e-01f, 3.2465247e-01f, 1.3533528e-01f,
  4.3936934e-02f, 1.1108997e-02f, 2.1874911e-03f, 3.3546263e-04f,
  4.0065297e-05f, 3.7266532e-06f, 2.6995785e-07f, 1.5229979e-08f,
  6.6915858e-10f, 2.2897490e-11f, 6.1019365e-13f, 1.2664166e-14f
};

// ---- kernel 1: per-block min/max partials; re-arms counters each launch ----
__global__ __launch_bounds__(1024) void minmax_kernel(const float* __restrict__ pred,
                                                      const float* __restrict__ tgt,
                                                      float2* __restrict__ mm,
                                                      unsigned* __restrict__ cnt) {
  __shared__ float smin[16], smax[16];
  const int tid = threadIdx.x, lane = tid & 63, wave = tid >> 6;
  if (blockIdx.x == 0 && tid < 12) cnt[tid] = 0u;   // re-armed every launch/replay
  const int pair = blockIdx.x >> 4, sub = blockIdx.x & 15;
  const float* src = pair < 8 ? pred + (size_t)pair * NPIX
                              : tgt  + (size_t)(pair - 8) * NPIX;
  const float4v* s4 = (const float4v*)src + sub * 4096;
  float vmin = 3.0e38f, vmax = -3.0e38f;
  #pragma unroll
  for (int k = 0; k < 4; ++k) {
    float4v v = s4[k * 1024 + tid];
    vmin = fminf(vmin, fminf(fminf(v[0], v[1]), fminf(v[2], v[3])));
    vmax = fmaxf(vmax, fmaxf(fmaxf(v[0], v[1]), fmaxf(v[2], v[3])));
  }
  #pragma unroll
  for (int off = 32; off; off >>= 1) {
    vmin = fminf(vmin, __shfl_xor(vmin, off));
    vmax = fmaxf(vmax, __shfl_xor(vmax, off));
  }
  if (lane == 0) { smin[wave] = vmin; smax[wave] = vmax; }
  __syncthreads();
  if (tid == 0) {
    float m = smin[0], M = smax[0];
    #pragma unroll
    for (int w = 1; w < 16; ++w) { m = fminf(m, smin[w]); M = fmaxf(M, smax[w]); }
    mm[blockIdx.x] = (float2){m, M};
  }
}

// ---- kernel 2 (fused): fine hist -> private partial -> last-block-per-batch
//      reduces 8 partials + runs conv1/conv2/marginals/MI; last tail block
//      writes the final mean. 64 blocks x 1024 thr. NO spinning anywhere:
//      non-last blocks simply exit (deadlock-impossible). All device-scope
//      fences are executed by tid0 ONLY (R2 post-mortem: per-thread fences
//      were the 100us catastrophe). Integer sums in fixed order -> the exact
//      same f32 values enter the convs -> bit-identical result.
__global__ __launch_bounds__(1024) void hist_tail_kernel(const float* __restrict__ pred,
                                                         const float* __restrict__ tgt,
                                                         const float2* __restrict__ mm,
                                                         unsigned* __restrict__ part,
                                                         float2* __restrict__ fineF,
                                                         unsigned* __restrict__ cnt,
                                                         float* __restrict__ mi,
                                                         float* __restrict__ out) {
  __shared__ float S[14608];   // tail scratch; phase-1 aliases first 32KB as u32 H[8192]
  __shared__ unsigned s_last;
  unsigned* H = (unsigned*)S;
  const int tid = threadIdx.x, lane = tid & 63, wave = tid >> 6;
  const int b = blockIdx.x >> 3, c = blockIdx.x & 7;

  // batch minmax from the 16 per-image partials
  float pmin = 3.0e38f, pmax = -3.0e38f, tmin = 3.0e38f, tmax = -3.0e38f;
  #pragma unroll
  for (int s2 = 0; s2 < 16; ++s2) {
    float2 a = mm[b * 16 + s2], d = mm[(8 + b) * 16 + s2];
    pmin = fminf(pmin, a.x); pmax = fmaxf(pmax, a.y);
    tmin = fminf(tmin, d.x); tmax = fmaxf(tmax, d.y);
  }
  const float sp = 126.0f / (pmax - pmin + 1e-10f), op = -pmin * sp + 0.5f;
  const float st = 126.0f / (tmax - tmin + 1e-10f), ot = -tmin * st + 0.5f;

  // ---- phase 1: bank-swizzled LDS hist of chunk (b,c), u16-packed ----
  ((uint4v*)H)[tid]        = (uint4v){0u, 0u, 0u, 0u};
  ((uint4v*)H)[1024 + tid] = (uint4v){0u, 0u, 0u, 0u};
  __syncthreads();

  const float4v* p4 = (const float4v*)(pred + (size_t)b * NPIX + (size_t)c * CHPX);
  const float4v* t4 = (const float4v*)(tgt  + (size_t)b * NPIX + (size_t)c * CHPX);
  #pragma unroll
  for (int it = 0; it < 8; ++it) {
    float4v vp = p4[it * 1024 + tid];
    float4v vt = t4[it * 1024 + tid];
    #pragma unroll
    for (int j = 0; j < 4; ++j) {
      int fp = (int)(vp[j] * sp + op);      // 0..126
      int ft = (int)(vt[j] * st + ot);
      int w  = (fp << 6) | (ft >> 1);
      atomicAdd(&H[w ^ ((fp & 7) << 2)], 1u << ((ft & 1) << 4));  // bank-swizzled
    }
  }
  __syncthreads();

  // flush private partial (un-swizzled -> linear layout), plain stores
  {
    uint4v* dst = (uint4v*)(part + ((size_t)blockIdx.x << 13));
    #pragma unroll
    for (int j = 0; j < 2; ++j) {
      int g = j * 1024 + tid;
      dst[g] = ((uint4v*)H)[g ^ ((g >> 4) & 7)];
    }
  }
  __syncthreads();                          // all waves' stores drained to L2
  if (tid == 0) {
    __threadfence();                        // tid0-only release: wb L2 -> device
    unsigned old = atomicAdd(&cnt[b], 1u);  // device-scope arrival
    s_last = (old == NCH - 1) ? 1u : 0u;
    if (s_last) __threadfence();            // tid0-only acquire: inv L1/L2
  }
  __syncthreads();
  if (!s_last) return;                      // non-last blocks exit (no spin)

  // ---- phase 2 (last block of batch b): reduce 8 partials -> fineF[b] ----
  {
    const unsigned* src = part + ((size_t)b << 16);   // 8 chunks x 8192 words
    float2* f2 = fineF + (size_t)b * 8192;
    #pragma unroll
    for (int q = 0; q < 8; ++q) {
      int w = q * 1024 + tid;               // word (fp<<6)|j
      unsigned lo = 0, hi = 0;
      #pragma unroll
      for (int cc = 0; cc < 8; ++cc) {
        unsigned v = src[((size_t)cc << 13) + w];
        lo += v & 0xFFFFu; hi += v >> 16;
      }
      float2 o; o.x = (float)lo; o.y = (float)hi;     // counts < 2^24: exact
      f2[w] = o;                            // cells (fp,2j), (fp,2j+1)
    }
    if (tid == 0) atomicExch(&cnt[b], 0u);  // self-reset (solo-replay safety)
  }
  __syncthreads();                          // own-CU read-after-write is coherent

  // ---- phase 3a: conv along fine-p rows, decimate x2 -> S[0,10304) ----
  const float* fineG = (const float*)(fineF + (size_t)b * 8192);  // f32 [128][128]
  {
    const int ft = tid & 127, r = tid >> 7;
    const float* fb = fineG + ft;
    float v[47];
    #pragma unroll
    for (int t = 0; t < 47; ++t) {
      int fp = 16 * r - 16 + t;
      v[t] = ((unsigned)fp < 128u) ? fb[fp << 7] : 0.0f;
    }
    float acc[8];
    #pragma unroll
    for (int d = 0; d < 8; ++d) {
      float a = 0.0f;
      #pragma unroll
      for (int k = 0; k < 33; ++k) a += WK[k] * v[2 * d + k];
      acc[d] = a;
    }
    #pragma unroll
    for (int d = 0; d < 8; ++d)
      S[(8 * r + d) * MPW + ft + 16] = acc[d];
    // zero guard columns: 64 rows x (16 left + 17 right)
    #pragma unroll
    for (int ii = 0; ii < 3; ++ii) {
      int idx = ii * 1024 + tid;
      if (idx < 64 * 33) {
        int rr = idx / 33, cc = idx % 33;
        int col = cc < 16 ? cc : cc + 128;
        S[rr * MPW + col] = 0.0f;
      }
    }
  }
  __syncthreads();

  // ---- phase 3b: conv along fine-t axis -> pxy ----
  const int i = tid & 63, js = (tid >> 6) << 2;
  {
    float v[39];
    #pragma unroll
    for (int t = 0; t < 39; ++t) v[t] = S[i * MPW + 2 * js + t];
    float acc[4] = {0.0f, 0.0f, 0.0f, 0.0f};
    #pragma unroll
    for (int d = 0; d < 4; ++d)
      #pragma unroll
      for (int k = 0; k < 33; ++k) acc[d] += WK[k] * v[2 * d + k];
    const float invN = 1.0f / (float)NPIX;
    #pragma unroll
    for (int d = 0; d < 4; ++d) S[10304 + i * 65 + js + d] = acc[d] * invN;
  }
  __syncthreads();

  // marginals: wave w owns 4 rows + 4 cols (16-lane groups)
  {
    const int l16 = lane & 15, sub16 = lane >> 4;
    int row = 4 * wave + sub16;
    float s = 0.0f;
    #pragma unroll
    for (int k = 0; k < 4; ++k) s += S[10304 + row * 65 + l16 * 4 + k];
    #pragma unroll
    for (int off = 8; off; off >>= 1) s += __shfl_xor(s, off);
    if (l16 == 0) S[14464 + row] = s;     // px
    float t2 = 0.0f;
    #pragma unroll
    for (int k = 0; k < 4; ++k) t2 += S[10304 + (l16 * 4 + k) * 65 + row];
    #pragma unroll
    for (int off = 8; off; off >>= 1) t2 += __shfl_xor(t2, off);
    if (l16 == 0) S[14528 + row] = t2;    // py
  }
  __syncthreads();

  float a = 0.0f;
  #pragma unroll
  for (int r = 0; r < 4; ++r) {
    int e = r * 1024 + tid;
    int ii = e >> 6, jj = e & 63;
    float pv = S[10304 + ii * 65 + jj];
    float d = S[14464 + ii] * S[14528 + jj] + 1e-10f;
    a += pv * __logf((pv + 1e-10f) / d);
  }
  #pragma unroll
  for (int off = 32; off; off >>= 1) a += __shfl_xor(a, off);
  if (lane == 0) S[14592 + wave] = a;
  __syncthreads();

  if (tid == 0) {
    float s = 0.0f;
    #pragma unroll
    for (int w = 0; w < 16; ++w) s += S[14592 + w];
    atomicExch(&mi[b], s);                 // device-scope store
    __threadfence();                       // tid0-only release
    unsigned prev = atomicAdd(&cnt[8], 1u);
    if (prev == NB - 1) {                  // last tail block finalizes
      __threadfence();                     // tid0-only acquire
      float tot = 0.0f;
      #pragma unroll
      for (int k = 0; k < NB; ++k) tot += atomicAdd(&mi[k], 0.0f);  // atomic read
      out[0] = -(tot * (1.0f / NB));
      atomicExch(&cnt[8], 0u);             // self-reset (solo-replay safety)
    }
  }
}

extern "C" void kernel_launch(void* const* d_in, const int* in_sizes, int n_in,
                              void* d_out, int out_size, void* d_ws, size_t ws_size,
                              hipStream_t stream) {
  const float* pred = (const float*)d_in[0];
  const float* tgt  = (const float*)d_in[1];
  float*    out  = (float*)d_out;
  float*    wsf  = (float*)d_ws;
  float2*   mm   = (float2*)d_ws;                      // 256 float2 in [0,512) floats
  float*    mi   = wsf + 512;                          // 8 floats
  unsigned* cnt  = (unsigned*)(wsf + 520);             // [0..7] batch, [8] final
  unsigned* part = (unsigned*)(wsf + HDR_FLOATS);      // NB*NCH*8192 words = 2MB
  float2*   fineF = (float2*)(wsf + HDR_FLOATS + (size_t)NB * NCH * 8192);  // 512KB

  minmax_kernel   <<<256,      1024, 0, stream>>>(pred, tgt, mm, cnt);
  hist_tail_kernel<<<NB * NCH, 1024, 0, stream>>>(pred, tgt, mm, part, fineF, cnt, mi, out);
}